// Round 13
// baseline (93.093 us; speedup 1.0000x reference)
//
#include <hip/hip_runtime.h>
#include <hip/hip_bf16.h>

typedef __hip_bfloat16 bf16;
typedef float f32x4 __attribute__((ext_vector_type(4)));
typedef short bf16x8 __attribute__((ext_vector_type(8)));   // 8 bf16 in 4 VGPRs
typedef int   int4v  __attribute__((ext_vector_type(4)));

constexpr int Bb = 2, Ss = 2048, Dd = 1024, Hh = 16, Ww = 128, HDd = 64;
constexpr int Mrows = Bb * Ss;   // 4096
constexpr int NT32 = Dd / 32;    // 32 K-steps of BK=32

// async global->LDS, 16B per lane; LDS dest = wave-uniform base + lane*16
__device__ __forceinline__ void gload16(const void* g, void* l) {
  __builtin_amdgcn_global_load_lds(
      (const __attribute__((address_space(1))) void*)g,
      (__attribute__((address_space(3))) void*)l, 16, 0, 0);
}

__device__ __forceinline__ f32x4 mfma16(bf16x8 a, bf16x8 b, f32x4 c) {
  return __builtin_amdgcn_mfma_f32_16x16x32_bf16(a, b, c, 0, 0, 0);
}

// ---------------------------------------------------------------- fused prep:
// z<4: transpose weight z ([K][N] fp32 -> bf16 [N][K] at out+z*Dd*Dd)
// z==4: convert x fp32 -> bf16
__global__ __launch_bounds__(256) void prep_k(const float* __restrict__ x,
                                              const float* __restrict__ W0,
                                              const float* __restrict__ W1,
                                              const float* __restrict__ W2,
                                              const float* __restrict__ W3,
                                              bf16* __restrict__ xb,
                                              bf16* __restrict__ Wt) {
  if (blockIdx.z == 4) {
    size_t blk = blockIdx.y * 32 + blockIdx.x;     // 0..1023
#pragma unroll
    for (int it = 0; it < 4; ++it) {
      size_t i = blk * 1024 + it * 256 + threadIdx.x;
      float4 v = reinterpret_cast<const float4*>(x)[i];
      union { bf16 b[4]; ushort4 u; } cv;
      cv.b[0] = __float2bfloat16(v.x);
      cv.b[1] = __float2bfloat16(v.y);
      cv.b[2] = __float2bfloat16(v.z);
      cv.b[3] = __float2bfloat16(v.w);
      reinterpret_cast<ushort4*>(xb)[i] = cv.u;
    }
    return;
  }
  const float* Win = (blockIdx.z == 0) ? W0 : (blockIdx.z == 1) ? W1
                     : (blockIdx.z == 2) ? W2 : W3;
  bf16* o = Wt + (size_t)blockIdx.z * Dd * Dd;
  __shared__ float tile[32][33];
  int bx = blockIdx.x, by = blockIdx.y;
  int tx = threadIdx.x & 31, ty = threadIdx.x >> 5;
#pragma unroll
  for (int i = 0; i < 4; ++i)
    tile[ty + i * 8][tx] = Win[(size_t)(by * 32 + ty + i * 8) * Dd + bx * 32 + tx];
  __syncthreads();
#pragma unroll
  for (int i = 0; i < 4; ++i)
    o[(size_t)(bx * 32 + ty + i * 8) * Dd + by * 32 + tx] =
        __float2bfloat16(tile[tx][ty + i * 8]);
}

// ---------------------------------------------------------------- 8-wave 128x128 GEMM core
// BK=32, QUAD-BUFFERED counted-vmcnt pipeline at PRESERVED occupancy:
// 4 bufs x 16 KB = 64 KB (2 blocks/CU), stage kt+3 during kt, raw s_barrier +
// counted vmcnt(4) (tail 2 -> 0) -> loads get ~3 steps of slack, never a full
// drain in steady state. 64B rows: two-level XOR mask (row^(row>>2))&3 spreads
// the 16-lane column read to 2-way bank aliasing (free, m136). gload16 dest
// stays linear (1KB/wave contiguous); source pre-swizzled.
__device__ __forceinline__ void gemm_core8(const bf16* __restrict__ A,
                                           const bf16* __restrict__ Bt,
                                           int bm, int bn,
                                           bf16* lds, f32x4 acc[2][4]) {
  const int t = threadIdx.x;
  const int lane = t & 63, w = t >> 6;
  const int wr = w >> 1, wc = w & 1;
  const int l15 = lane & 15, l16 = lane >> 4;
  const bf16* Arow0 = A + (size_t)bm * 128 * Dd;
  const bf16* Brow0 = Bt + (size_t)bn * 128 * Dd;

  auto stage = [&](int buf, int kt) {        // 2 gload16 per thread
    int ci = t;                              // 0..511: row=ci>>2, chunk=ci&3
    int row = ci >> 2, pc = ci & 3;
    int sc = pc ^ ((row ^ (row >> 2)) & 3);  // inverse-swizzled source chunk
    gload16(Arow0 + (size_t)row * Dd + kt * 32 + sc * 8, lds + buf * 8192 + ci * 8);
    gload16(Brow0 + (size_t)row * Dd + kt * 32 + sc * 8, lds + buf * 8192 + 4096 + ci * 8);
  };

  stage(0, 0); stage(1, 1); stage(2, 2);     // 6 loads in flight
  asm volatile("s_waitcnt vmcnt(4)" ::: "memory");   // buf0 landed; 1,2 in flight
  __builtin_amdgcn_s_barrier();
  __builtin_amdgcn_sched_barrier(0);

  for (int kt = 0; kt < NT32; ++kt) {
    if (kt + 3 < NT32) stage((kt + 3) & 3, kt + 3);  // 3 steps of slack
    const bf16* Ab = lds + (kt & 3) * 8192;
    const bf16* Bb = Ab + 4096;
    bf16x8 af[2], bfr[4];
#pragma unroll
    for (int m = 0; m < 2; ++m) {
      int row = wr * 32 + m * 16 + l15;
      int mc = (row ^ (row >> 2)) & 3;
      af[m] = *reinterpret_cast<const bf16x8*>(Ab + row * 32 + ((l16 ^ mc) * 8));
    }
#pragma unroll
    for (int n = 0; n < 4; ++n) {
      int row = wc * 64 + n * 16 + l15;
      int mc = (row ^ (row >> 2)) & 3;
      bfr[n] = *reinterpret_cast<const bf16x8*>(Bb + row * 32 + ((l16 ^ mc) * 8));
    }
    __builtin_amdgcn_s_setprio(1);
#pragma unroll
    for (int m = 0; m < 2; ++m)
#pragma unroll
      for (int n = 0; n < 4; ++n)
        acc[m][n] = mfma16(af[m], bfr[n], acc[m][n]);
    __builtin_amdgcn_s_setprio(0);
    // counted wait: require buf kt+1 landed; newer stages stay in flight
    if (kt + 3 < NT32)      asm volatile("s_waitcnt vmcnt(4)" ::: "memory");
    else if (kt + 2 < NT32) asm volatile("s_waitcnt vmcnt(2)" ::: "memory");
    else                    asm volatile("s_waitcnt vmcnt(0)" ::: "memory");
    __builtin_amdgcn_s_barrier();            // all waves' kt+1 chunks visible
    __builtin_amdgcn_sched_barrier(0);       // pin next ds_reads behind barrier
  }
}

// ---------------------------------------------------------------- fused QKV projection
// L2 super-tiled block mapping (R12): per XCD, 4bm x 6bn super-tiles.
__global__ __launch_bounds__(512) void gemm_qkv8w(const bf16* __restrict__ A,
                                                  const bf16* __restrict__ Wt3,
                                                  const float* __restrict__ bq,
                                                  const float* __restrict__ bk,
                                                  const float* __restrict__ bv,
                                                  bf16* __restrict__ Qh,
                                                  bf16* __restrict__ Kh,
                                                  bf16* __restrict__ Vt) {
  __shared__ __align__(16) bf16 lds[32768];  // 64 KB: 4 bufs x (A 4096 + B 4096)
  f32x4 acc[2][4] = {};
  int id = blockIdx.x;                     // 768 blocks
  int xcd = id & 7, j = id >> 3;           // j = 0..95 per XCD
  int sb = j / 24, rem = j % 24;           // 4 bn-super-tiles of 6
  int bm = xcd * 4 + rem / 6;              // 0..31
  int bn = sb * 6 + rem % 6;               // 0..23
  gemm_core8(A, Wt3, bm, bn, lds, acc);

  const int lane = threadIdx.x & 63, w = threadIdx.x >> 6;
  const int wr = w >> 1, wc = w & 1, l15 = lane & 15, l16 = lane >> 4;
  const int p = bn >> 3;                   // 0=Q, 1=K, 2=V (block-uniform)
  const int c0w = (bn & 7) * 128 + wc * 64;  // wave col base within projection
  const int h = c0w >> 6;                  // one head per wave

  if (p < 2) {
    // staging LDS is dead after the core's final barrier -> reuse as repack
    bf16 (*rep)[72] = reinterpret_cast<bf16(*)[72]>(lds + w * (16 * 72));
    bf16* dst = p ? Kh : Qh;
    const float* bp = p ? bk : bq;
    float bi[4];
#pragma unroll
    for (int n = 0; n < 4; ++n) bi[n] = bp[c0w + n * 16 + l15];
#pragma unroll
    for (int m = 0; m < 2; ++m) {
#pragma unroll
      for (int n = 0; n < 4; ++n)
#pragma unroll
        for (int r = 0; r < 4; ++r)
          rep[l16 * 4 + r][n * 16 + l15] = __float2bfloat16(acc[m][n][r] + bi[n]);
      // same-wave write->read through LDS (in-order DS pipe + compiler lgkmcnt)
      int rrow = lane >> 2, rch = lane & 3;
      int sg = bm * 128 + wr * 32 + m * 16 + rrow;
      int b = sg >> 11, sl = sg & (Ss - 1);
      bf16* base = dst + (((size_t)(b * Hh + h)) * Ss + sl) * HDd;
      bf16x8 v0 = *reinterpret_cast<const bf16x8*>(&rep[rrow][rch * 8]);
      bf16x8 v1 = *reinterpret_cast<const bf16x8*>(&rep[rrow][(rch + 4) * 8]);
      *reinterpret_cast<bf16x8*>(base + rch * 8) = v0;
      *reinterpret_cast<bf16x8*>(base + (rch + 4) * 8) = v1;
    }
  } else {
#pragma unroll
    for (int n = 0; n < 4; ++n) {
      int col = c0w + n * 16 + l15;
      int hh = col >> 6, hd = col & (HDd - 1);
      float bi = bv[col];
#pragma unroll
      for (int m = 0; m < 2; ++m) {
        int s0 = bm * 128 + wr * 32 + m * 16 + l16 * 4;
        int b = s0 >> 11, sl = s0 & (Ss - 1);
        union { ushort4 u; ushort e[4]; } pk;
#pragma unroll
        for (int r = 0; r < 4; ++r) {
          bf16 tb = __float2bfloat16(acc[m][n][r] + bi);
          pk.e[r] = *reinterpret_cast<ushort*>(&tb);
        }
        *reinterpret_cast<ushort4*>(&Vt[(((size_t)(b * Hh + hh)) * HDd + hd) * Ss + sl]) = pk.u;
      }
    }
  }
}

// ---------------------------------------------------------------- O projection (8-wave, quad-buf)
__global__ __launch_bounds__(512) void gemm_o8w(const bf16* __restrict__ AO,
                                                const bf16* __restrict__ WtO,
                                                const float* __restrict__ bo,
                                                const float* __restrict__ resid,
                                                float* __restrict__ out) {
  __shared__ __align__(16) bf16 lds[32768];
  f32x4 acc[2][4] = {};
  int id = blockIdx.x;                     // 256 blocks
  int wg = (id & 7) * 32 + (id >> 3);
  int bm = wg >> 3, bn = wg & 7;           // per XCD: bn-inner (WtO 2MB fits L2)
  gemm_core8(AO, WtO, bm, bn, lds, acc);

  const int lane = threadIdx.x & 63, w = threadIdx.x >> 6;
  const int wr = w >> 1, wc = w & 1, l15 = lane & 15, l16 = lane >> 4;
#pragma unroll
  for (int m = 0; m < 2; ++m)
#pragma unroll
    for (int n = 0; n < 4; ++n) {
      int col = bn * 128 + wc * 64 + n * 16 + l15;
      float bi = bo[col];
#pragma unroll
      for (int r = 0; r < 4; ++r) {
        int row = bm * 128 + wr * 32 + m * 16 + l16 * 4 + r;
        size_t idx = (size_t)row * Dd + col;
        out[idx] = acc[m][n][r] + bi + resid[idx];
      }
    }
}

// ---------------------------------------------------------------- local attention
// 128-query blocks, 8 waves. K staged in LDS (gload16 + both-sides XOR swizzle);
// V^T read directly from global (L2-resident). Per-wave P window in LDS.
// LDS 74 KB -> 2 blocks/CU.  [R10/R12, unchanged]
__global__ __launch_bounds__(512) void attn_local2(const bf16* __restrict__ Q,
                                                   const bf16* __restrict__ K,
                                                   const bf16* __restrict__ Vt,
                                                   bf16* __restrict__ AO) {
  __shared__ __align__(16) bf16 Kl[256 * 64];     // 32 KB, rows 128B, swizzled
  __shared__ bf16 Ps[8][16][168];                 // 42 KB, per-wave P window
  const int t = threadIdx.x, lane = t & 63, w = t >> 6;
  const int l15 = lane & 15, l16 = lane >> 4;
  const int qb = blockIdx.x, h = blockIdx.y, b = blockIdx.z;
  const int q0 = qb * 128, kstart = q0 - 128;     // key span [kstart, kstart+256)
  const bf16* Qp = Q + ((size_t)(b * Hh + h)) * Ss * HDd;
  const bf16* Kp = K + ((size_t)(b * Hh + h)) * Ss * HDd;
  const bf16* Vp = Vt + ((size_t)(b * Hh + h)) * HDd * Ss;

  // stage K[256][64]: 2048 x 16B chunks; physical chunk pc holds global pc^(row&7)
#pragma unroll
  for (int i = 0; i < 4; ++i) {
    int ci = i * 512 + t;
    int row = ci >> 3, pc = ci & 7;
    int sc = pc ^ (row & 7);
    int key = kstart + row;
    if (key < 0) key = 0;                  // clamped rows are masked later
    gload16(Kp + (size_t)key * HDd + sc * 8, (bf16*)Kl + ci * 8);
  }

  // Q fragments (global, before the barrier so latency overlaps staging)
  const int qrow = q0 + w * 16 + l15;
  bf16x8 aq0 = *reinterpret_cast<const bf16x8*>(Qp + (size_t)qrow * HDd + l16 * 8);
  bf16x8 aq1 = *reinterpret_cast<const bf16x8*>(Qp + (size_t)qrow * HDd + 32 + l16 * 8);

  __syncthreads();                          // staging drained + visible

  // QK^T: wave w needs key tiles w..w+8 (rel to kstart)
  f32x4 sc9[9];
  __builtin_amdgcn_s_setprio(1);
#pragma unroll
  for (int j = 0; j < 9; ++j) {
    int krow = (w + j) * 16 + l15;          // 0..255
    bf16x8 bk0 = *reinterpret_cast<const bf16x8*>(
        Kl + krow * 64 + (((0 + l16) ^ (krow & 7)) * 8));
    bf16x8 bk1 = *reinterpret_cast<const bf16x8*>(
        Kl + krow * 64 + (((4 + l16) ^ (krow & 7)) * 8));
    f32x4 s = {};
    s = mfma16(aq0, bk0, s);
    s = mfma16(aq1, bk1, s);
    sc9[j] = s;
  }
  __builtin_amdgcn_s_setprio(0);

  // mask + scale + softmax (D-layout: row=(l>>4)*4+r, col=l&15)
  const float scale = 0.125f;
  float mrow[4], ssum[4], inv[4];
  int qg[4];
#pragma unroll
  for (int r = 0; r < 4; ++r) { mrow[r] = -1e30f; qg[r] = q0 + w * 16 + l16 * 4 + r; }
#pragma unroll
  for (int j = 0; j < 9; ++j) {
    int kg = kstart + (w + j) * 16 + l15;
#pragma unroll
    for (int r = 0; r < 4; ++r) {
      bool valid = (kg >= 0) && (kg <= qg[r]) && (qg[r] - kg < Ww);
      float v = valid ? sc9[j][r] * scale : -1e9f;
      sc9[j][r] = v;
      mrow[r] = fmaxf(mrow[r], v);
    }
  }
#pragma unroll
  for (int r = 0; r < 4; ++r)
#pragma unroll
    for (int off = 1; off < 16; off <<= 1)
      mrow[r] = fmaxf(mrow[r], __shfl_xor(mrow[r], off));
#pragma unroll
  for (int r = 0; r < 4; ++r) ssum[r] = 0.f;
#pragma unroll
  for (int j = 0; j < 9; ++j)
#pragma unroll
    for (int r = 0; r < 4; ++r) {
      float p = __expf(sc9[j][r] - mrow[r]);
      sc9[j][r] = p;
      ssum[r] += p;
    }
#pragma unroll
  for (int r = 0; r < 4; ++r)
#pragma unroll
    for (int off = 1; off < 16; off <<= 1)
      ssum[r] += __shfl_xor(ssum[r], off);
#pragma unroll
  for (int r = 0; r < 4; ++r) inv[r] = 1.f / ssum[r];

  // unnormalized P -> per-wave LDS window (tiles tb..tb+9, tb = w-(w&1))
#pragma unroll
  for (int j = 0; j < 9; ++j) {
    int lt = j + (w & 1);
#pragma unroll
    for (int r = 0; r < 4; ++r)
      Ps[w][l16 * 4 + r][lt * 16 + l15] = __float2bfloat16(sc9[j][r]);
  }
  {
    int ltz = (w & 1) ? 0 : 9;
    bf16 z16 = __float2bfloat16(0.f);
#pragma unroll
    for (int r = 0; r < 4; ++r)
      Ps[w][l16 * 4 + r][ltz * 16 + l15] = z16;
  }
  // same-wave write->read through LDS (in-order DS pipe + compiler lgkmcnt)

  // P @ V: V^T fragments straight from global (L2 hits; 2 blocks/CU hides latency)
  f32x4 o[4] = {};
  __builtin_amdgcn_s_setprio(1);
#pragma unroll
  for (int cc = 0; cc < 5; ++cc) {
    bf16x8 pf = *reinterpret_cast<const bf16x8*>(&Ps[w][l15][cc * 32 + l16 * 8]);
    int kk = kstart + ((w >> 1) + cc) * 32 + l16 * 8;
    int kc = kk < 0 ? 0 : kk;               // whole-chunk invalid => P==0 anyway
#pragma unroll
    for (int ht = 0; ht < 4; ++ht) {
      bf16x8 vf = *reinterpret_cast<const bf16x8*>(Vp + (size_t)(ht * 16 + l15) * Ss + kc);
      o[ht] = mfma16(pf, vf, o[ht]);
    }
  }
  __builtin_amdgcn_s_setprio(0);

  // normalize and write merged-head layout
#pragma unroll
  for (int ht = 0; ht < 4; ++ht)
#pragma unroll
    for (int r = 0; r < 4; ++r) {
      int qw = q0 + w * 16 + l16 * 4 + r;
      int col = h * HDd + ht * 16 + l15;
      AO[(size_t)(b * Ss + qw) * Dd + col] = __float2bfloat16(o[ht][r] * inv[r]);
    }
}

// ---------------------------------------------------------------- LayerNorm (in-place)
__global__ __launch_bounds__(256) void ln_inplace(float* __restrict__ y,
                                                  const float* __restrict__ gamma,
                                                  const float* __restrict__ beta) {
  int row = blockIdx.x;
  float* yr = y + (size_t)row * Dd;
  float4 v = reinterpret_cast<const float4*>(yr)[threadIdx.x];
  float s = v.x + v.y + v.z + v.w;
  float s2 = v.x * v.x + v.y * v.y + v.z * v.z + v.w * v.w;
#pragma unroll
  for (int off = 1; off < 64; off <<= 1) {
    s += __shfl_xor(s, off);
    s2 += __shfl_xor(s2, off);
  }
  __shared__ float r1[4], r2[4];
  int w = threadIdx.x >> 6;
  if ((threadIdx.x & 63) == 0) { r1[w] = s; r2[w] = s2; }
  __syncthreads();
  s = r1[0] + r1[1] + r1[2] + r1[3];
  s2 = r2[0] + r2[1] + r2[2] + r2[3];
  float mu = s * (1.f / Dd);
  float var = s2 * (1.f / Dd) - mu * mu;
  float rs = rsqrtf(var + 1e-5f);
  float4 g = reinterpret_cast<const float4*>(gamma)[threadIdx.x];
  float4 be = reinterpret_cast<const float4*>(beta)[threadIdx.x];
  float4 o;
  o.x = (v.x - mu) * rs * g.x + be.x;
  o.y = (v.y - mu) * rs * g.y + be.y;
  o.z = (v.z - mu) * rs * g.z + be.z;
  o.w = (v.w - mu) * rs * g.w + be.w;
  reinterpret_cast<float4*>(yr)[threadIdx.x] = o;
}

// ---------------------------------------------------------------- launch
extern "C" void kernel_launch(void* const* d_in, const int* in_sizes, int n_in,
                              void* d_out, int out_size, void* d_ws, size_t ws_size,
                              hipStream_t stream) {
  const float* x     = (const float*)d_in[0];
  const float* Wq    = (const float*)d_in[1];
  const float* bq    = (const float*)d_in[2];
  const float* Wk    = (const float*)d_in[3];
  const float* bk    = (const float*)d_in[4];
  const float* Wv    = (const float*)d_in[5];
  const float* bv    = (const float*)d_in[6];
  const float* Wo    = (const float*)d_in[7];
  const float* bo    = (const float*)d_in[8];
  const float* gamma = (const float*)d_in[9];
  const float* beta  = (const float*)d_in[10];
  float* out = (float*)d_out;

  char* ws = (char*)d_ws;
  bf16* xb  = (bf16*)(ws + (size_t)0);          // 8 MB
  bf16* Wt3 = (bf16*)(ws + ((size_t)8  << 20)); // [3072][1024] QKV + [1024][1024] O
  bf16* WtO = (bf16*)(ws + ((size_t)14 << 20));
  bf16* Qh  = (bf16*)(ws + ((size_t)16 << 20)); // [b][h][s][hd]
  bf16* Kh  = (bf16*)(ws + ((size_t)24 << 20)); // [b][h][s][hd]
  bf16* Vt  = (bf16*)(ws + ((size_t)32 << 20)); // [b][h][hd][s]
  bf16* AO  = (bf16*)(ws + ((size_t)40 << 20)); // [b][s][d]

  prep_k<<<dim3(32, 32, 5), 256, 0, stream>>>(x, Wq, Wk, Wv, Wo, xb, Wt3);

  gemm_qkv8w<<<768, 512, 0, stream>>>(xb, Wt3, bq, bk, bv, Qh, Kh, Vt);

  attn_local2<<<dim3(Ss / 128, Hh, Bb), 512, 0, stream>>>(Qh, Kh, Vt, AO);

  gemm_o8w<<<256, 512, 0, stream>>>(AO, WtO, bo, x, out);
  ln_inplace<<<Mrows, 256, 0, stream>>>(out, gamma, beta);
}

// Round 14
// 83.152 us; speedup vs baseline: 1.1196x; 1.1196x over previous
//
#include <hip/hip_runtime.h>
#include <hip/hip_bf16.h>

typedef __hip_bfloat16 bf16;
typedef float f32x4 __attribute__((ext_vector_type(4)));
typedef short bf16x8 __attribute__((ext_vector_type(8)));   // 8 bf16 in 4 VGPRs
typedef int   int4v  __attribute__((ext_vector_type(4)));

constexpr int Bb = 2, Ss = 2048, Dd = 1024, Hh = 16, Ww = 128, HDd = 64;
constexpr int Mrows = Bb * Ss;   // 4096
constexpr int NTk = Dd / 64;     // 16 K-steps of BK=64

// async global->LDS, 16B per lane; LDS dest = wave-uniform base + lane*16
__device__ __forceinline__ void gload16(const void* g, void* l) {
  __builtin_amdgcn_global_load_lds(
      (const __attribute__((address_space(1))) void*)g,
      (__attribute__((address_space(3))) void*)l, 16, 0, 0);
}

__device__ __forceinline__ f32x4 mfma16(bf16x8 a, bf16x8 b, f32x4 c) {
  return __builtin_amdgcn_mfma_f32_16x16x32_bf16(a, b, c, 0, 0, 0);
}

// ---------------------------------------------------------------- fused prep:
// z<4: transpose weight z ([K][N] fp32 -> bf16 [N][K] at out+z*Dd*Dd)
// z==4: convert x fp32 -> bf16
__global__ __launch_bounds__(256) void prep_k(const float* __restrict__ x,
                                              const float* __restrict__ W0,
                                              const float* __restrict__ W1,
                                              const float* __restrict__ W2,
                                              const float* __restrict__ W3,
                                              bf16* __restrict__ xb,
                                              bf16* __restrict__ Wt) {
  if (blockIdx.z == 4) {
    size_t blk = blockIdx.y * 32 + blockIdx.x;     // 0..1023
#pragma unroll
    for (int it = 0; it < 4; ++it) {
      size_t i = blk * 1024 + it * 256 + threadIdx.x;
      float4 v = reinterpret_cast<const float4*>(x)[i];
      union { bf16 b[4]; ushort4 u; } cv;
      cv.b[0] = __float2bfloat16(v.x);
      cv.b[1] = __float2bfloat16(v.y);
      cv.b[2] = __float2bfloat16(v.z);
      cv.b[3] = __float2bfloat16(v.w);
      reinterpret_cast<ushort4*>(xb)[i] = cv.u;
    }
    return;
  }
  const float* Win = (blockIdx.z == 0) ? W0 : (blockIdx.z == 1) ? W1
                     : (blockIdx.z == 2) ? W2 : W3;
  bf16* o = Wt + (size_t)blockIdx.z * Dd * Dd;
  __shared__ float tile[32][33];
  int bx = blockIdx.x, by = blockIdx.y;
  int tx = threadIdx.x & 31, ty = threadIdx.x >> 5;
#pragma unroll
  for (int i = 0; i < 4; ++i)
    tile[ty + i * 8][tx] = Win[(size_t)(by * 32 + ty + i * 8) * Dd + bx * 32 + tx];
  __syncthreads();
#pragma unroll
  for (int i = 0; i < 4; ++i)
    o[(size_t)(bx * 32 + ty + i * 8) * Dd + by * 32 + tx] =
        __float2bfloat16(tile[tx][ty + i * 8]);
}

// ---------------------------------------------------------------- 8-wave 128x128 GEMM core
// BK=64, double-buffered (R6/R10/R12 best-known): issue next-tile global_load_lds
// BEFORE ds_read+MFMA, one __syncthreads per K-step. Both-sides XOR-8 swizzle.
// LDS 64 KB -> 2 blocks/CU.
__device__ __forceinline__ void gemm_core8(const bf16* __restrict__ A,
                                           const bf16* __restrict__ Bt,
                                           int bm, int bn,
                                           bf16* lds, f32x4 acc[2][4]) {
  const int t = threadIdx.x;
  const int lane = t & 63, w = t >> 6;
  const int wr = w >> 1, wc = w & 1;
  const int l15 = lane & 15, l16 = lane >> 4;
  const bf16* Arow0 = A + (size_t)bm * 128 * Dd;
  const bf16* Brow0 = Bt + (size_t)bn * 128 * Dd;

  auto stage = [&](int buf, int kt) {
#pragma unroll
    for (int i = 0; i < 2; ++i) {
      int ci = i * 512 + t;                 // 0..1023 chunks of 16B
      int row = ci >> 3, pc = ci & 7;
      int sc = pc ^ (row & 7);              // inverse-swizzled source chunk
      gload16(Arow0 + (size_t)row * Dd + kt * 64 + sc * 8, lds + buf * 16384 + ci * 8);
      gload16(Brow0 + (size_t)row * Dd + kt * 64 + sc * 8, lds + buf * 16384 + 8192 + ci * 8);
    }
  };

  stage(0, 0);
  __syncthreads();                          // drains vmcnt for tile 0
  int buf = 0;
  for (int kt = 0; kt < NTk; ++kt) {
    if (kt + 1 < NTk) stage(buf ^ 1, kt + 1);   // loads fly under compute
    bf16x8 af[2][2], bfr[4][2];
    const bf16* Ab = lds + buf * 16384;
    const bf16* Bb = Ab + 8192;
#pragma unroll
    for (int m = 0; m < 2; ++m) {
      int row = wr * 32 + m * 16 + l15;
#pragma unroll
      for (int kk = 0; kk < 2; ++kk)
        af[m][kk] = *reinterpret_cast<const bf16x8*>(
            Ab + row * 64 + (((kk * 4 + l16) ^ (row & 7)) * 8));
    }
#pragma unroll
    for (int n = 0; n < 4; ++n) {
      int row = wc * 64 + n * 16 + l15;
#pragma unroll
      for (int kk = 0; kk < 2; ++kk)
        bfr[n][kk] = *reinterpret_cast<const bf16x8*>(
            Bb + row * 64 + (((kk * 4 + l16) ^ (row & 7)) * 8));
    }
    __builtin_amdgcn_s_setprio(1);
#pragma unroll
    for (int m = 0; m < 2; ++m)
#pragma unroll
      for (int n = 0; n < 4; ++n) {
        acc[m][n] = mfma16(af[m][0], bfr[n][0], acc[m][n]);
        acc[m][n] = mfma16(af[m][1], bfr[n][1], acc[m][n]);
      }
    __builtin_amdgcn_s_setprio(0);
    __syncthreads();                        // drains next-tile loads + read sync
    buf ^= 1;
  }
}

// ---------------------------------------------------------------- fused QKV projection
// L2 super-tiled block mapping (R12): per XCD, 4bm x 6bn super-tiles.
__global__ __launch_bounds__(512) void gemm_qkv8w(const bf16* __restrict__ A,
                                                  const bf16* __restrict__ Wt3,
                                                  const float* __restrict__ bq,
                                                  const float* __restrict__ bk,
                                                  const float* __restrict__ bv,
                                                  bf16* __restrict__ Qh,
                                                  bf16* __restrict__ Kh,
                                                  bf16* __restrict__ Vt) {
  __shared__ __align__(16) bf16 lds[32768];  // 64 KB: 2 bufs x (A 8192 + B 8192)
  f32x4 acc[2][4] = {};
  int id = blockIdx.x;                     // 768 blocks
  int xcd = id & 7, j = id >> 3;           // j = 0..95 per XCD
  int sb = j / 24, rem = j % 24;           // 4 bn-super-tiles of 6
  int bm = xcd * 4 + rem / 6;              // 0..31
  int bn = sb * 6 + rem % 6;               // 0..23
  gemm_core8(A, Wt3, bm, bn, lds, acc);

  const int lane = threadIdx.x & 63, w = threadIdx.x >> 6;
  const int wr = w >> 1, wc = w & 1, l15 = lane & 15, l16 = lane >> 4;
  const int p = bn >> 3;                   // 0=Q, 1=K, 2=V (block-uniform)
  const int c0w = (bn & 7) * 128 + wc * 64;  // wave col base within projection
  const int h = c0w >> 6;                  // one head per wave

  if (p < 2) {
    // staging LDS is dead after the core's final barrier -> reuse as repack
    bf16 (*rep)[72] = reinterpret_cast<bf16(*)[72]>(lds + w * (16 * 72));
    bf16* dst = p ? Kh : Qh;
    const float* bp = p ? bk : bq;
    float bi[4];
#pragma unroll
    for (int n = 0; n < 4; ++n) bi[n] = bp[c0w + n * 16 + l15];
#pragma unroll
    for (int m = 0; m < 2; ++m) {
#pragma unroll
      for (int n = 0; n < 4; ++n)
#pragma unroll
        for (int r = 0; r < 4; ++r)
          rep[l16 * 4 + r][n * 16 + l15] = __float2bfloat16(acc[m][n][r] + bi[n]);
      // same-wave write->read through LDS (in-order DS pipe + compiler lgkmcnt)
      int rrow = lane >> 2, rch = lane & 3;
      int sg = bm * 128 + wr * 32 + m * 16 + rrow;
      int b = sg >> 11, sl = sg & (Ss - 1);
      bf16* base = dst + (((size_t)(b * Hh + h)) * Ss + sl) * HDd;
      bf16x8 v0 = *reinterpret_cast<const bf16x8*>(&rep[rrow][rch * 8]);
      bf16x8 v1 = *reinterpret_cast<const bf16x8*>(&rep[rrow][(rch + 4) * 8]);
      *reinterpret_cast<bf16x8*>(base + rch * 8) = v0;
      *reinterpret_cast<bf16x8*>(base + (rch + 4) * 8) = v1;
    }
  } else {
#pragma unroll
    for (int n = 0; n < 4; ++n) {
      int col = c0w + n * 16 + l15;
      int hh = col >> 6, hd = col & (HDd - 1);
      float bi = bv[col];
#pragma unroll
      for (int m = 0; m < 2; ++m) {
        int s0 = bm * 128 + wr * 32 + m * 16 + l16 * 4;
        int b = s0 >> 11, sl = s0 & (Ss - 1);
        union { ushort4 u; ushort e[4]; } pk;
#pragma unroll
        for (int r = 0; r < 4; ++r) {
          bf16 tb = __float2bfloat16(acc[m][n][r] + bi);
          pk.e[r] = *reinterpret_cast<ushort*>(&tb);
        }
        *reinterpret_cast<ushort4*>(&Vt[(((size_t)(b * Hh + hh)) * HDd + hd) * Ss + sl]) = pk.u;
      }
    }
  }
}

// ---------------------------------------------------------------- O projection (8-wave, dbuf)
// Residual from bf16 xb; y written as bf16 into workspace (LN finishes in fp32).
__global__ __launch_bounds__(512) void gemm_o8w(const bf16* __restrict__ AO,
                                                const bf16* __restrict__ WtO,
                                                const float* __restrict__ bo,
                                                const bf16* __restrict__ residb,
                                                bf16* __restrict__ yb) {
  __shared__ __align__(16) bf16 lds[32768];
  f32x4 acc[2][4] = {};
  int id = blockIdx.x;                     // 256 blocks
  int wg = (id & 7) * 32 + (id >> 3);
  int bm = wg >> 3, bn = wg & 7;           // per XCD: bn-inner (WtO 2MB fits L2)
  gemm_core8(AO, WtO, bm, bn, lds, acc);

  const int lane = threadIdx.x & 63, w = threadIdx.x >> 6;
  const int wr = w >> 1, wc = w & 1, l15 = lane & 15, l16 = lane >> 4;
#pragma unroll
  for (int m = 0; m < 2; ++m)
#pragma unroll
    for (int n = 0; n < 4; ++n) {
      int col = bn * 128 + wc * 64 + n * 16 + l15;
      float bi = bo[col];
#pragma unroll
      for (int r = 0; r < 4; ++r) {
        int row = bm * 128 + wr * 32 + m * 16 + l16 * 4 + r;
        size_t idx = (size_t)row * Dd + col;
        float v = acc[m][n][r] + bi + __bfloat162float(residb[idx]);
        yb[idx] = __float2bfloat16(v);
      }
    }
}

// ---------------------------------------------------------------- local attention
// 128-query blocks, 8 waves. K staged in LDS (gload16 + both-sides XOR swizzle);
// V^T read directly from global (L2-resident). Per-wave P window in LDS.
// LDS 74 KB -> 2 blocks/CU.  [R10/R12, unchanged]
__global__ __launch_bounds__(512) void attn_local2(const bf16* __restrict__ Q,
                                                   const bf16* __restrict__ K,
                                                   const bf16* __restrict__ Vt,
                                                   bf16* __restrict__ AO) {
  __shared__ __align__(16) bf16 Kl[256 * 64];     // 32 KB, rows 128B, swizzled
  __shared__ bf16 Ps[8][16][168];                 // 42 KB, per-wave P window
  const int t = threadIdx.x, lane = t & 63, w = t >> 6;
  const int l15 = lane & 15, l16 = lane >> 4;
  const int qb = blockIdx.x, h = blockIdx.y, b = blockIdx.z;
  const int q0 = qb * 128, kstart = q0 - 128;     // key span [kstart, kstart+256)
  const bf16* Qp = Q + ((size_t)(b * Hh + h)) * Ss * HDd;
  const bf16* Kp = K + ((size_t)(b * Hh + h)) * Ss * HDd;
  const bf16* Vp = Vt + ((size_t)(b * Hh + h)) * HDd * Ss;

  // stage K[256][64]: 2048 x 16B chunks; physical chunk pc holds global pc^(row&7)
#pragma unroll
  for (int i = 0; i < 4; ++i) {
    int ci = i * 512 + t;
    int row = ci >> 3, pc = ci & 7;
    int sc = pc ^ (row & 7);
    int key = kstart + row;
    if (key < 0) key = 0;                  // clamped rows are masked later
    gload16(Kp + (size_t)key * HDd + sc * 8, (bf16*)Kl + ci * 8);
  }

  // Q fragments (global, before the barrier so latency overlaps staging)
  const int qrow = q0 + w * 16 + l15;
  bf16x8 aq0 = *reinterpret_cast<const bf16x8*>(Qp + (size_t)qrow * HDd + l16 * 8);
  bf16x8 aq1 = *reinterpret_cast<const bf16x8*>(Qp + (size_t)qrow * HDd + 32 + l16 * 8);

  __syncthreads();                          // staging drained + visible

  // QK^T: wave w needs key tiles w..w+8 (rel to kstart)
  f32x4 sc9[9];
  __builtin_amdgcn_s_setprio(1);
#pragma unroll
  for (int j = 0; j < 9; ++j) {
    int krow = (w + j) * 16 + l15;          // 0..255
    bf16x8 bk0 = *reinterpret_cast<const bf16x8*>(
        Kl + krow * 64 + (((0 + l16) ^ (krow & 7)) * 8));
    bf16x8 bk1 = *reinterpret_cast<const bf16x8*>(
        Kl + krow * 64 + (((4 + l16) ^ (krow & 7)) * 8));
    f32x4 s = {};
    s = mfma16(aq0, bk0, s);
    s = mfma16(aq1, bk1, s);
    sc9[j] = s;
  }
  __builtin_amdgcn_s_setprio(0);

  // mask + scale + softmax (D-layout: row=(l>>4)*4+r, col=l&15)
  const float scale = 0.125f;
  float mrow[4], ssum[4], inv[4];
  int qg[4];
#pragma unroll
  for (int r = 0; r < 4; ++r) { mrow[r] = -1e30f; qg[r] = q0 + w * 16 + l16 * 4 + r; }
#pragma unroll
  for (int j = 0; j < 9; ++j) {
    int kg = kstart + (w + j) * 16 + l15;
#pragma unroll
    for (int r = 0; r < 4; ++r) {
      bool valid = (kg >= 0) && (kg <= qg[r]) && (qg[r] - kg < Ww);
      float v = valid ? sc9[j][r] * scale : -1e9f;
      sc9[j][r] = v;
      mrow[r] = fmaxf(mrow[r], v);
    }
  }
#pragma unroll
  for (int r = 0; r < 4; ++r)
#pragma unroll
    for (int off = 1; off < 16; off <<= 1)
      mrow[r] = fmaxf(mrow[r], __shfl_xor(mrow[r], off));
#pragma unroll
  for (int r = 0; r < 4; ++r) ssum[r] = 0.f;
#pragma unroll
  for (int j = 0; j < 9; ++j)
#pragma unroll
    for (int r = 0; r < 4; ++r) {
      float p = __expf(sc9[j][r] - mrow[r]);
      sc9[j][r] = p;
      ssum[r] += p;
    }
#pragma unroll
  for (int r = 0; r < 4; ++r)
#pragma unroll
    for (int off = 1; off < 16; off <<= 1)
      ssum[r] += __shfl_xor(ssum[r], off);
#pragma unroll
  for (int r = 0; r < 4; ++r) inv[r] = 1.f / ssum[r];

  // unnormalized P -> per-wave LDS window (tiles tb..tb+9, tb = w-(w&1))
#pragma unroll
  for (int j = 0; j < 9; ++j) {
    int lt = j + (w & 1);
#pragma unroll
    for (int r = 0; r < 4; ++r)
      Ps[w][l16 * 4 + r][lt * 16 + l15] = __float2bfloat16(sc9[j][r]);
  }
  {
    int ltz = (w & 1) ? 0 : 9;
    bf16 z16 = __float2bfloat16(0.f);
#pragma unroll
    for (int r = 0; r < 4; ++r)
      Ps[w][l16 * 4 + r][ltz * 16 + l15] = z16;
  }
  // same-wave write->read through LDS (in-order DS pipe + compiler lgkmcnt)

  // P @ V: V^T fragments straight from global (L2 hits; 2 blocks/CU hides latency)
  f32x4 o[4] = {};
  __builtin_amdgcn_s_setprio(1);
#pragma unroll
  for (int cc = 0; cc < 5; ++cc) {
    bf16x8 pf = *reinterpret_cast<const bf16x8*>(&Ps[w][l15][cc * 32 + l16 * 8]);
    int kk = kstart + ((w >> 1) + cc) * 32 + l16 * 8;
    int kc = kk < 0 ? 0 : kk;               // whole-chunk invalid => P==0 anyway
#pragma unroll
    for (int ht = 0; ht < 4; ++ht) {
      bf16x8 vf = *reinterpret_cast<const bf16x8*>(Vp + (size_t)(ht * 16 + l15) * Ss + kc);
      o[ht] = mfma16(pf, vf, o[ht]);
    }
  }
  __builtin_amdgcn_s_setprio(0);

  // normalize and write merged-head layout
#pragma unroll
  for (int ht = 0; ht < 4; ++ht)
#pragma unroll
    for (int r = 0; r < 4; ++r) {
      int qw = q0 + w * 16 + l16 * 4 + r;
      int col = h * HDd + ht * 16 + l15;
      AO[(size_t)(b * Ss + qw) * Dd + col] = __float2bfloat16(o[ht][r] * inv[r]);
    }
}

// ---------------------------------------------------------------- LayerNorm (bf16 y -> fp32 out)
__global__ __launch_bounds__(256) void ln_b(const bf16* __restrict__ yb,
                                            const float* __restrict__ gamma,
                                            const float* __restrict__ beta,
                                            float* __restrict__ out) {
  int row = blockIdx.x;
  const bf16* yr = yb + (size_t)row * Dd;
  union { ushort4 u; ushort e[4]; } raw;
  raw.u = reinterpret_cast<const ushort4*>(yr)[threadIdx.x];
  float v0 = __bfloat162float(*reinterpret_cast<const bf16*>(&raw.e[0]));
  float v1 = __bfloat162float(*reinterpret_cast<const bf16*>(&raw.e[1]));
  float v2 = __bfloat162float(*reinterpret_cast<const bf16*>(&raw.e[2]));
  float v3 = __bfloat162float(*reinterpret_cast<const bf16*>(&raw.e[3]));
  float s = v0 + v1 + v2 + v3;
  float s2 = v0 * v0 + v1 * v1 + v2 * v2 + v3 * v3;
#pragma unroll
  for (int off = 1; off < 64; off <<= 1) {
    s += __shfl_xor(s, off);
    s2 += __shfl_xor(s2, off);
  }
  __shared__ float r1[4], r2[4];
  int w = threadIdx.x >> 6;
  if ((threadIdx.x & 63) == 0) { r1[w] = s; r2[w] = s2; }
  __syncthreads();
  s = r1[0] + r1[1] + r1[2] + r1[3];
  s2 = r2[0] + r2[1] + r2[2] + r2[3];
  float mu = s * (1.f / Dd);
  float var = s2 * (1.f / Dd) - mu * mu;
  float rs = rsqrtf(var + 1e-5f);
  float4 g = reinterpret_cast<const float4*>(gamma)[threadIdx.x];
  float4 be = reinterpret_cast<const float4*>(beta)[threadIdx.x];
  float4 o;
  o.x = (v0 - mu) * rs * g.x + be.x;
  o.y = (v1 - mu) * rs * g.y + be.y;
  o.z = (v2 - mu) * rs * g.z + be.z;
  o.w = (v3 - mu) * rs * g.w + be.w;
  reinterpret_cast<float4*>(out + (size_t)row * Dd)[threadIdx.x] = o;
}

// ---------------------------------------------------------------- launch
extern "C" void kernel_launch(void* const* d_in, const int* in_sizes, int n_in,
                              void* d_out, int out_size, void* d_ws, size_t ws_size,
                              hipStream_t stream) {
  const float* x     = (const float*)d_in[0];
  const float* Wq    = (const float*)d_in[1];
  const float* bq    = (const float*)d_in[2];
  const float* Wk    = (const float*)d_in[3];
  const float* bk    = (const float*)d_in[4];
  const float* Wv    = (const float*)d_in[5];
  const float* bv    = (const float*)d_in[6];
  const float* Wo    = (const float*)d_in[7];
  const float* bo    = (const float*)d_in[8];
  const float* gamma = (const float*)d_in[9];
  const float* beta  = (const float*)d_in[10];
  float* out = (float*)d_out;

  char* ws = (char*)d_ws;
  bf16* xb  = (bf16*)(ws + (size_t)0);          // 8 MB
  bf16* Wt3 = (bf16*)(ws + ((size_t)8  << 20)); // [3072][1024] QKV + [1024][1024] O
  bf16* WtO = (bf16*)(ws + ((size_t)14 << 20));
  bf16* Qh  = (bf16*)(ws + ((size_t)16 << 20)); // [b][h][s][hd]; reused as yb
  bf16* Kh  = (bf16*)(ws + ((size_t)24 << 20)); // [b][h][s][hd]
  bf16* Vt  = (bf16*)(ws + ((size_t)32 << 20)); // [b][h][hd][s]
  bf16* AO  = (bf16*)(ws + ((size_t)40 << 20)); // [b][s][d]
  bf16* yb  = Qh;                               // Qh dead after attn

  prep_k<<<dim3(32, 32, 5), 256, 0, stream>>>(x, Wq, Wk, Wv, Wo, xb, Wt3);

  gemm_qkv8w<<<768, 512, 0, stream>>>(xb, Wt3, bq, bk, bv, Qh, Kh, Vt);

  attn_local2<<<dim3(Ss / 128, Hh, Bb), 512, 0, stream>>>(Qh, Kh, Vt, AO);

  gemm_o8w<<<256, 512, 0, stream>>>(AO, WtO, bo, xb, yb);
  ln_b<<<Mrows, 256, 0, stream>>>(yb, gamma, beta, out);
}